// Round 6
// baseline (582.798 us; speedup 1.0000x reference)
//
#include <hip/hip_runtime.h>

#define T_STEPS 256
#define BATCH   1000
#define D_IN    300
#define H4      8
#define NF4     75            // float4 per row (300 floats)
#define RPB     128           // rows per tile (64 quads x 2 rows)
#define NTILE   2000          // NTILE * RPB = 256000 rows = T*B
#define NPROD   512           // persistent producer blocks (2/CU)
#define NCONS   8             // consumer blocks (8*256 = 2048 lanes >= 2*BATCH)
#define GOLDEN  0x3A701B4D    // tile-done token (flags are zeroed pre-launch)

#define L2E   1.4426950408889634f   // log2(e)
#define L2E2  2.8853900817779268f   // 2*log2(e)

// ---------------------------------------------------------------------------
// helpers
// ---------------------------------------------------------------------------
__device__ __forceinline__ float fexp2(float x) {
#if __has_builtin(__builtin_amdgcn_exp2f)
    return __builtin_amdgcn_exp2f(x);     // raw v_exp_f32
#else
    return exp2f(x);
#endif
}
__device__ __forceinline__ float sig2(float x) {       // in: log2e-scaled
    return __builtin_amdgcn_rcpf(1.0f + fexp2(-x));
}
__device__ __forceinline__ float tanh2(float x) {      // in: 2*log2e-scaled
    return fmaf(-2.0f, __builtin_amdgcn_rcpf(1.0f + fexp2(x)), 1.0f);
}
__device__ __forceinline__ float dot4acc(float4 a, float4 b, float acc) {
    return fmaf(a.x, b.x, fmaf(a.y, b.y, fmaf(a.z, b.z, fmaf(a.w, b.w, acc))));
}
// swap adjacent lanes (0<->1, 2<->3) via DPP quad_perm [1,0,3,2]: pure VALU.
__device__ __forceinline__ float swap1(float x) {
#if __has_builtin(__builtin_amdgcn_mov_dpp)
    return __int_as_float(
        __builtin_amdgcn_mov_dpp(__float_as_int(x), 0xB1, 0xF, 0xF, true));
#else
    return __shfl_xor(x, 1);
#endif
}
__device__ __forceinline__ void acq_fence() {
#if __has_builtin(__builtin_amdgcn_fence)
    __builtin_amdgcn_fence(__ATOMIC_ACQUIRE, "agent");
#else
    __threadfence();
#endif
}

// Frontier poll: RELAXED ballot scan of flags[F..F+63]; advance by the
// contiguous-GOLDEN prefix; ONE acquire fence after the grant (fence-based
// acquire: orders the later plain xg reads, emits the cache invalidate once
// per grant instead of per poll). Wave-uniform control flow throughout.
__device__ __forceinline__ void ensure(int need, int& F, int& granted,
                                       const int* flags, int lane) {
    if (granted >= need) return;
    while (granted < need) {
        int idx = F + lane;
        if (idx >= NTILE) idx = NTILE - 1;
        int v = __hip_atomic_load(&flags[idx], __ATOMIC_RELAXED,
                                  __HIP_MEMORY_SCOPE_AGENT);
        unsigned long long nm = ~__ballot(v == GOLDEN);
        int adv = nm ? (int)__builtin_ctzll(nm) : 64;
        if (adv == 0) __builtin_amdgcn_s_sleep(8);
        F += adv;
        if (F > NTILE) F = NTILE;
        granted = (F * RPB) / BATCH;        // full steps available
    }
    acq_fence();
}

// ---------------------------------------------------------------------------
// Fused producer/consumer kernel.
// Producers (blocks 0..NPROD-1, tile-stride so the frontier advances ~NPROD
// tiles/round): round-4 xproj math -- quad owns 2 rows x 8 gates, x read once
// HBM->VGPR, W broadcast from 9.6KB LDS, quad butterfly, output layout
// xg[row][u][i,f,g,o] pre-scaled into the exp2 domain. Per tile:
// __syncthreads (drains stores) + agent-scope RELEASE store flag[tile]=GOLDEN.
// Consumers (blocks NPROD..): 2-lane-per-element LSTM scan in static 4-step
// groups, one-group-ahead prefetch in NAMED registers (no runtime-indexed
// array -> no scratch), one poll+fence per group.
// Consumer waits on producer only -- deadlock-free by construction.
// ---------------------------------------------------------------------------
__global__ __launch_bounds__(256) void fused_kernel(
    const float* __restrict__ x, const float* __restrict__ W,
    const float* __restrict__ b_ih, const float* __restrict__ b_hh,
    const float* __restrict__ h0in, const float* __restrict__ c0in,
    const float* __restrict__ Whh0, const float* __restrict__ Wih1,
    const float* __restrict__ Whh1, const float* __restrict__ bih1,
    const float* __restrict__ bhh1, const float* __restrict__ Wlin,
    const float* __restrict__ blin,
    float* __restrict__ xg, int* flags,
    float* __restrict__ out)
{
    __shared__ __align__(16) float4 ws4[H4 * NF4];   // 9.6 KB (producers only)

    if (blockIdx.x < NPROD) {
        // ================= producer =================
        const int tid = threadIdx.x;
        const float4* __restrict__ w4 = (const float4*)W;
        for (int k = tid; k < H4 * NF4; k += 256)
            ws4[k] = w4[k];
        __syncthreads();

        const int  lane = tid & 3;
        const int  quad = tid >> 2;
        const float b0 = b_ih[2 * lane]     + b_hh[2 * lane];
        const float b1 = b_ih[2 * lane + 1] + b_hh[2 * lane + 1];
        const float sc = (lane == 2) ? L2E2 : L2E;

        for (int tile = blockIdx.x; tile < NTILE; tile += NPROD) {
            const long row0 = (long)tile * RPB + (long)quad * 2;
            const float4* __restrict__ x0 = (const float4*)x + row0 * NF4;
            const float4* __restrict__ x1 = x0 + NF4;

            float acc0[H4], acc1[H4];
#pragma unroll
            for (int g = 0; g < H4; ++g) { acc0[g] = 0.f; acc1[g] = 0.f; }

            // i = 0..17: k = 4i+lane < 75 -> no guard
#pragma unroll 3
            for (int i = 0; i < 18; ++i) {
                const int k = 4 * i + lane;
                float4 xa = x0[k];
                float4 xb = x1[k];
#pragma unroll
                for (int g = 0; g < H4; ++g) {
                    float4 wv = ws4[g * NF4 + k];
                    acc0[g] = dot4acc(xa, wv, acc0[g]);
                    acc1[g] = dot4acc(xb, wv, acc1[g]);
                }
            }
            {   // epilogue: k = 72+lane, valid for lane < 3
                const int k = 72 + lane;
                if (k < NF4) {
                    float4 xa = x0[k];
                    float4 xb = x1[k];
#pragma unroll
                    for (int g = 0; g < H4; ++g) {
                        float4 wv = ws4[g * NF4 + k];
                        acc0[g] = dot4acc(xa, wv, acc0[g]);
                        acc1[g] = dot4acc(xb, wv, acc1[g]);
                    }
                }
            }

            // quad-local butterfly
#pragma unroll
            for (int g = 0; g < H4; ++g) {
                acc0[g] += __shfl_xor(acc0[g], 1);
                acc0[g] += __shfl_xor(acc0[g], 2);
                acc1[g] += __shfl_xor(acc1[g], 1);
                acc1[g] += __shfl_xor(acc1[g], 2);
            }

            // layout: xg[row*8 + u*4 + s]; lane l = slot s
            xg[row0 * 8 + lane]           = (acc0[2 * lane]     + b0) * sc;
            xg[row0 * 8 + 4 + lane]       = (acc0[2 * lane + 1] + b1) * sc;
            xg[(row0 + 1) * 8 + lane]     = (acc1[2 * lane]     + b0) * sc;
            xg[(row0 + 1) * 8 + 4 + lane] = (acc1[2 * lane + 1] + b1) * sc;

            __syncthreads();   // all threads' xg stores drained (vmcnt 0)
            if (tid == 0)
                __hip_atomic_store(&flags[tile], GOLDEN,
                                   __ATOMIC_RELEASE, __HIP_MEMORY_SCOPE_AGENT);
        }
    } else {
        // ================= consumer =================
        const int cg    = (blockIdx.x - NPROD) * 256 + threadIdx.x;  // 0..2047
        const int e_raw = cg >> 1;
        const int u     = cg & 1;
        const bool wr   = (e_raw < BATCH) && (u == 0);
        const int  e    = (e_raw < BATCH) ? e_raw : (BATCH - 1);
        const int  lane = threadIdx.x & 63;

        // Per-lane weights: slot s in {i,f,g,o} -> gate row 2s+u.
        // wa* multiplies OWN h, wb* multiplies PARTNER h.
        float wa0[4], wb0[4], wa1i[4], wb1i[4], wa1h[4], wb1h[4], bs1[4];
#pragma unroll
        for (int s = 0; s < 4; ++s) {
            const int   row = 2 * s + u;
            const float f   = (s == 2) ? L2E2 : L2E;
            wa0[s]  = Whh0[row * 2 + u]       * f;
            wb0[s]  = Whh0[row * 2 + (1 - u)] * f;
            wa1i[s] = Wih1[row * 2 + u]       * f;
            wb1i[s] = Wih1[row * 2 + (1 - u)] * f;
            wa1h[s] = Whh1[row * 2 + u]       * f;
            wb1h[s] = Whh1[row * 2 + (1 - u)] * f;
            bs1[s]  = (bih1[row] + bhh1[row]) * f;
        }

        float h0 = h0in[2 * e + u];
        float c0 = c0in[2 * e + u];
        float h1 = h0in[2 * BATCH + 2 * e + u];
        float c1 = c0in[2 * BATCH + 2 * e + u];

        const float4* __restrict__ xq = (const float4*)xg;
        const long base = (long)e * 2 + u;

        float h1o = swap1(h1);
        float p[4];
#pragma unroll
        for (int s = 0; s < 4; ++s)
            p[s] = bs1[s] + h1 * wa1h[s] + h1o * wb1h[s];

        // one full LSTM step (both layers + partial hoist), xv = step input
#define LSTEP(xv)                                                        \
        {                                                                \
            const float h0o = swap1(h0);                                 \
            const float gi = (xv).x + h0 * wa0[0] + h0o * wb0[0];        \
            const float gf = (xv).y + h0 * wa0[1] + h0o * wb0[1];        \
            const float gg = (xv).z + h0 * wa0[2] + h0o * wb0[2];        \
            const float go = (xv).w + h0 * wa0[3] + h0o * wb0[3];        \
            c0 = sig2(gf) * c0 + sig2(gi) * tanh2(gg);                   \
            h0 = sig2(go) * tanh2(c0 * L2E2);                            \
            const float h0n = swap1(h0);                                 \
            const float qi = p[0] + h0 * wa1i[0] + h0n * wb1i[0];        \
            const float qf = p[1] + h0 * wa1i[1] + h0n * wb1i[1];        \
            const float qg = p[2] + h0 * wa1i[2] + h0n * wb1i[2];        \
            const float qo = p[3] + h0 * wa1i[3] + h0n * wb1i[3];        \
            c1 = sig2(qf) * c1 + sig2(qi) * tanh2(qg);                   \
            h1 = sig2(qo) * tanh2(c1 * L2E2);                            \
            const float h1n = swap1(h1);                                 \
            p[0] = bs1[0] + h1 * wa1h[0] + h1n * wb1h[0];                \
            p[1] = bs1[1] + h1 * wa1h[1] + h1n * wb1h[1];                \
            p[2] = bs1[2] + h1 * wa1h[2] + h1n * wb1h[2];                \
            p[3] = bs1[3] + h1 * wa1h[3] + h1n * wb1h[3];                \
        }

        int F = 0, granted = 0;
        ensure(4, F, granted, flags, lane);
        float4 q0 = xq[(long)0 * 2 * BATCH + base];
        float4 q1 = xq[(long)1 * 2 * BATCH + base];
        float4 q2 = xq[(long)2 * 2 * BATCH + base];
        float4 q3 = xq[(long)3 * 2 * BATCH + base];

        for (int tb = 0; tb < T_STEPS; tb += 4) {
            const bool more = (tb + 4) < T_STEPS;
            float4 n0, n1, n2, n3;
            if (more) {
                int need = tb + 8; if (need > T_STEPS) need = T_STEPS;
                ensure(need, F, granted, flags, lane);
                n0 = xq[(long)(tb + 4) * 2 * BATCH + base];
                n1 = xq[(long)(tb + 5) * 2 * BATCH + base];
                n2 = xq[(long)(tb + 6) * 2 * BATCH + base];
                n3 = xq[(long)(tb + 7) * 2 * BATCH + base];
            }
            LSTEP(q0); LSTEP(q1); LSTEP(q2); LSTEP(q3);
            if (more) { q0 = n0; q1 = n1; q2 = n2; q3 = n3; }
        }
#undef LSTEP

        const float h1b = swap1(h1);
        if (wr)
            out[e] = h1 * Wlin[0] + h1b * Wlin[1] + blin[0];
    }
}

extern "C" void kernel_launch(void* const* d_in, const int* in_sizes, int n_in,
                              void* d_out, int out_size, void* d_ws, size_t ws_size,
                              hipStream_t stream) {
    const float* x      = (const float*)d_in[0];
    const float* h0     = (const float*)d_in[1];
    const float* c0     = (const float*)d_in[2];
    const float* W_ih0  = (const float*)d_in[3];
    const float* W_hh0  = (const float*)d_in[4];
    const float* b_ih0  = (const float*)d_in[5];
    const float* b_hh0  = (const float*)d_in[6];
    const float* W_ih1  = (const float*)d_in[7];
    const float* W_hh1  = (const float*)d_in[8];
    const float* b_ih1  = (const float*)d_in[9];
    const float* b_hh1  = (const float*)d_in[10];
    const float* W_lin  = (const float*)d_in[11];
    const float* b_lin  = (const float*)d_in[12];
    float* out = (float*)d_out;

    float* xg    = (float*)d_ws;                                  // 8.192 MB
    int*   flags = (int*)((char*)d_ws
                          + (size_t)T_STEPS * BATCH * H4 * sizeof(float));

    // Zero the flag region every launch (graph-capturable async op): removes
    // any dependence on harness poison values / first-run ws contents.
    hipMemsetAsync(flags, 0, NTILE * sizeof(int), stream);

    fused_kernel<<<NPROD + NCONS, 256, 0, stream>>>(
        x, W_ih0, b_ih0, b_hh0, h0, c0, W_hh0, W_ih1, W_hh1,
        b_ih1, b_hh1, W_lin, b_lin, xg, flags, out);
}